// Round 2
// baseline (755.105 us; speedup 1.0000x reference)
//
#include <hip/hip_runtime.h>
#include <stdint.h>

// ---------- helpers ----------
typedef __attribute__((ext_vector_type(8))) short short8;   // 8 x bf16 (4 VGPRs)
typedef __attribute__((ext_vector_type(4))) float floatx4;  // MFMA accum

__device__ __forceinline__ unsigned short f2bf(float f) {
  union { float f; unsigned int u; } c; c.f = f;
  unsigned int u = c.u;
  unsigned int r = (u + 0x7fffu + ((u >> 16) & 1u)) >> 16;  // RNE
  return (unsigned short)r;
}
__device__ __forceinline__ float bf2f(unsigned short h) {
  union { unsigned int u; float f; } c; c.u = ((unsigned int)h) << 16;
  return c.f;
}

// async global->LDS, 16B per lane. LDS dest is wave-uniform base + lane*16.
__device__ __forceinline__ void load16_to_lds(const void* g, void* l) {
  __builtin_amdgcn_global_load_lds(
      (const __attribute__((address_space(1))) unsigned int*)g,
      (__attribute__((address_space(3))) unsigned int*)l, 16, 0, 0);
}

// ---------- elementwise kernels ----------
__global__ void f32_to_bf16_kernel(const float* __restrict__ in,
                                   unsigned short* __restrict__ out, long n4) {
  long i = blockIdx.x * (long)blockDim.x + threadIdx.x;
  if (i >= n4) return;
  float4 v = ((const float4*)in)[i];
  ushort4 o;
  o.x = f2bf(v.x); o.y = f2bf(v.y); o.z = f2bf(v.z); o.w = f2bf(v.w);
  ((ushort4*)out)[i] = o;
}

// w[n,k] (fp8 values stored as fp32) * s[n/128, k/128] -> bf16
__global__ void dequant_kernel(const float* __restrict__ wq,
                               const float* __restrict__ s,
                               unsigned short* __restrict__ out,
                               int K, int sK, long n4) {
  long i = blockIdx.x * (long)blockDim.x + threadIdx.x;
  if (i >= n4) return;
  long e = i * 4;
  int n = (int)(e / K);
  int k = (int)(e - (long)n * K);
  float sc = s[(n >> 7) * sK + (k >> 7)];
  float4 v = ((const float4*)wq)[i];
  ushort4 o;
  o.x = f2bf(v.x * sc); o.y = f2bf(v.y * sc);
  o.z = f2bf(v.z * sc); o.w = f2bf(v.w * sc);
  ((ushort4*)out)[i] = o;
}

// ---------- GEMM: C[M,N] = A[M,K] * B[N,K]^T, bf16 in, fp32 accum ----------
// 128x128 tile / block, 256 threads = 4 waves (2x2), each wave 64x64 via
// 4x4 grid of mfma_f32_16x16x32_bf16. m97-style 2-barrier K-loop with
// global_load_lds width-16 staging.
//
// XCD-aware swizzle: 1D grid, xcd = bid & 7 (empirical round-robin on
// MI355X). Each XCD owns an N-strip of nTiles/8 column tiles (B-strip
// ~3.5 MB stays resident in its 4 MB L2); traversal is M-major within the
// strip so each A-tile is fetched once from L3 and reused by the strip's
// blocks. Cuts per-GEMM L3 traffic ~10x (perf-only heuristic: if the
// bid->XCD mapping changes, only locality degrades).
//
// MODE: 0 = fp32 out, 1 = bf16 out, 2 = bf16 out fused with silu(gate)*acc
template <int MODE>
__global__ __launch_bounds__(256) void gemm_nt(
    const unsigned short* __restrict__ A,  // [M,K] bf16
    const unsigned short* __restrict__ B,  // [N,K] bf16
    void* __restrict__ C,                  // [M,N] fp32 or bf16
    const unsigned short* __restrict__ gate,  // [M,N] bf16 (MODE 2)
    int M, int N, int K) {
  __shared__ unsigned short As[128 * 32];
  __shared__ unsigned short Bs[128 * 32];

  const int tid = threadIdx.x;
  const int lane = tid & 63;
  const int wave = tid >> 6;
  const int wm = wave >> 1, wn = wave & 1;

  // --- XCD swizzle: bid -> (m0, n0) ---
  const int nTiles = N >> 7;           // multiple of 8 for our shapes
  const int nPerX = nTiles >> 3;       // strip width per XCD
  const int bid = blockIdx.x;
  const int xcd = bid & 7;
  const int idx = bid >> 3;            // 0 .. mTiles*nPerX-1
  const int mT = idx / nPerX;
  const int nL = idx - mT * nPerX;
  const int m0 = mT * 128;
  const int n0 = (xcd * nPerX + nL) * 128;

  // staging: flat [128][32] row-major; thread t covers 8 bf16 at flat t*8
  const int f0 = tid * 8;
  const int ar = f0 >> 5;   // row 0..63 (chunk 0), +64 for chunk 1
  const int ac = f0 & 31;

  const int q = lane >> 4;    // quad 0..3 -> k offset q*8
  const int r16 = lane & 15;  // row/col within 16

  floatx4 acc[4][4];
#pragma unroll
  for (int i = 0; i < 4; i++)
#pragma unroll
    for (int j = 0; j < 4; j++) acc[i][j] = (floatx4){0.f, 0.f, 0.f, 0.f};

  const unsigned short* Abase = A + (size_t)m0 * K;
  const unsigned short* Bbase = B + (size_t)n0 * K;

  for (int k0 = 0; k0 < K; k0 += 32) {
    load16_to_lds(Abase + (size_t)ar * K + k0 + ac, &As[f0]);
    load16_to_lds(Abase + (size_t)(64 + ar) * K + k0 + ac, &As[2048 + f0]);
    load16_to_lds(Bbase + (size_t)ar * K + k0 + ac, &Bs[f0]);
    load16_to_lds(Bbase + (size_t)(64 + ar) * K + k0 + ac, &Bs[2048 + f0]);
    __syncthreads();

    short8 a[4], b[4];
#pragma unroll
    for (int t = 0; t < 4; t++) {
      a[t] = *(const short8*)&As[(wm * 64 + t * 16 + r16) * 32 + q * 8];
      b[t] = *(const short8*)&Bs[(wn * 64 + t * 16 + r16) * 32 + q * 8];
    }
#pragma unroll
    for (int i = 0; i < 4; i++)
#pragma unroll
      for (int j = 0; j < 4; j++)
        acc[i][j] =
            __builtin_amdgcn_mfma_f32_16x16x32_bf16(a[i], b[j], acc[i][j], 0, 0, 0);
    __syncthreads();
  }

  // epilogue: D col = lane&15, row = quad*4 + reg (m89/m91-verified)
#pragma unroll
  for (int i = 0; i < 4; i++) {
    int row0 = m0 + wm * 64 + i * 16 + q * 4;
#pragma unroll
    for (int j = 0; j < 4; j++) {
      int col = n0 + wn * 64 + j * 16 + r16;
#pragma unroll
      for (int rr = 0; rr < 4; rr++) {
        size_t off = (size_t)(row0 + rr) * N + col;
        if (MODE == 0) {
          ((float*)C)[off] = acc[i][j][rr];
        } else if (MODE == 1) {
          ((unsigned short*)C)[off] = f2bf(acc[i][j][rr]);
        } else {
          float gv = bf2f(gate[off]);
          float sv = gv / (1.f + __expf(-gv));
          ((unsigned short*)C)[off] = f2bf(sv * acc[i][j][rr]);
        }
      }
    }
  }
}

// ---------- launch ----------
extern "C" void kernel_launch(void* const* d_in, const int* in_sizes, int n_in,
                              void* d_out, int out_size, void* d_ws, size_t ws_size,
                              hipStream_t stream) {
  const float* x = (const float*)d_in[0];
  const float* w1q = (const float*)d_in[1];
  const float* w1s = (const float*)d_in[2];
  const float* w3q = (const float*)d_in[3];
  const float* w3s = (const float*)d_in[4];
  const float* w2q = (const float*)d_in[5];
  const float* w2s = (const float*)d_in[6];

  const int T = 4096, H = 2048, F = 7168;

  char* ws = (char*)d_ws;
  unsigned short* xb = (unsigned short*)ws;  ws += (size_t)T * H * 2;   // 16.8 MB
  unsigned short* wb = (unsigned short*)ws;  ws += (size_t)F * H * 2;   // 29.4 MB (reused w1/w3/w2)
  unsigned short* g  = (unsigned short*)ws;  ws += (size_t)T * F * 2;   // 58.7 MB
  // total ~105 MB of d_ws

  long xn4 = (long)T * H / 4;
  long wn4 = (long)F * H / 4;

  f32_to_bf16_kernel<<<(xn4 + 255) / 256, 256, 0, stream>>>(x, xb, xn4);

  // g = x @ w1^T   (bf16 out)
  dequant_kernel<<<(wn4 + 255) / 256, 256, 0, stream>>>(w1q, w1s, wb, H, H / 128, wn4);
  gemm_nt<1><<<(F / 128) * (T / 128), 256, 0, stream>>>(xb, wb, g, nullptr, T, F, H);

  // g = silu(g) * (x @ w3^T)   (fused epilogue, in-place over g)
  dequant_kernel<<<(wn4 + 255) / 256, 256, 0, stream>>>(w3q, w3s, wb, H, H / 128, wn4);
  gemm_nt<2><<<(F / 128) * (T / 128), 256, 0, stream>>>(xb, wb, g, g, T, F, H);

  // out = g @ w2^T  (fp32 out)
  dequant_kernel<<<(wn4 + 255) / 256, 256, 0, stream>>>(w2q, w2s, wb, F, F / 128, wn4);
  gemm_nt<0><<<(H / 128) * (T / 128), 256, 0, stream>>>(g, wb, d_out, nullptr, T, H, F);
}

// Round 4
// 642.187 us; speedup vs baseline: 1.1758x; 1.1758x over previous
//
#include <hip/hip_runtime.h>
#include <stdint.h>

// ---------- helpers ----------
typedef __attribute__((ext_vector_type(8))) short short8;   // 8 x bf16 (4 VGPRs)
typedef __attribute__((ext_vector_type(4))) float floatx4;  // MFMA accum

__device__ __forceinline__ unsigned short f2bf(float f) {
  union { float f; unsigned int u; } c; c.f = f;
  unsigned int u = c.u;
  unsigned int r = (u + 0x7fffu + ((u >> 16) & 1u)) >> 16;  // RNE
  return (unsigned short)r;
}
__device__ __forceinline__ float bf2f(unsigned short h) {
  union { unsigned int u; float f; } c; c.u = ((unsigned int)h) << 16;
  return c.f;
}

// async global->LDS, 16B per lane. LDS dest is wave-uniform base + lane*16.
__device__ __forceinline__ void load16_to_lds(const void* g, void* l) {
  __builtin_amdgcn_global_load_lds(
      (const __attribute__((address_space(1))) unsigned int*)g,
      (__attribute__((address_space(3))) unsigned int*)l, 16, 0, 0);
}

// ---------- elementwise kernels ----------
__global__ void f32_to_bf16_kernel(const float* __restrict__ in,
                                   unsigned short* __restrict__ out, long n4) {
  long i = blockIdx.x * (long)blockDim.x + threadIdx.x;
  if (i >= n4) return;
  float4 v = ((const float4*)in)[i];
  ushort4 o;
  o.x = f2bf(v.x); o.y = f2bf(v.y); o.z = f2bf(v.z); o.w = f2bf(v.w);
  ((ushort4*)out)[i] = o;
}

// w[n,k] (fp8 values stored as fp32) * s[n/128, k/128] -> bf16
__global__ void dequant_kernel(const float* __restrict__ wq,
                               const float* __restrict__ s,
                               unsigned short* __restrict__ out,
                               int K, int sK, long n4) {
  long i = blockIdx.x * (long)blockDim.x + threadIdx.x;
  if (i >= n4) return;
  long e = i * 4;
  int n = (int)(e / K);
  int k = (int)(e - (long)n * K);
  float sc = s[(n >> 7) * sK + (k >> 7)];
  float4 v = ((const float4*)wq)[i];
  ushort4 o;
  o.x = f2bf(v.x * sc); o.y = f2bf(v.y * sc);
  o.z = f2bf(v.z * sc); o.w = f2bf(v.w * sc);
  ((ushort4*)out)[i] = o;
}

// ---------- merged dual GEMM + silu: C = silu(A*B1^T) .* (A*B3^T) ----------
// One block = one 128x128 output tile of the fused activation. A-tile staged
// ONCE per K-step for both GEMMs (saves a full pass over A vs two kernels),
// g/u never round-trip through memory, silu applied on fp32 accumulators.
// 512 threads = 8 waves; wave-tile 64(M)x32(N) for BOTH g and u:
//   acc 64 VGPR + a-frags 16 + b-frags 16 ≈ 120 regs -> launch_bounds(512,4)
//   pins 4 waves/SIMD = 16 waves/CU (2 blocks/CU), vs ~7 waves/CU in R1.
// Staging: 3x global_load_lds(16B)/thread per K32-step for 16 MFMAs/wave
// (m97 structure needs 4/thread for the same 16) -> lower VALU per MFMA.
__global__ __launch_bounds__(512, 4) void dual_gemm_silu(
    const unsigned short* __restrict__ A,   // [M,K] bf16 (x)
    const unsigned short* __restrict__ B1,  // [N,K] bf16 (w1)
    const unsigned short* __restrict__ B3,  // [N,K] bf16 (w3)
    unsigned short* __restrict__ C,         // [M,N] bf16 fused
    int M, int N, int K) {
  __shared__ unsigned short As[128 * 32];
  __shared__ unsigned short B1s[128 * 32];
  __shared__ unsigned short B3s[128 * 32];

  const int tid = threadIdx.x;
  const int lane = tid & 63;
  const int wave = tid >> 6;      // 0..7
  const int wm = wave >> 2;       // 0..1  (M 64-half)
  const int wn = wave & 3;        // 0..3  (N 32-quarter)
  const int m0 = blockIdx.y * 128, n0 = blockIdx.x * 128;

  // staging map: flat [128][32], thread t -> 16B at flat t*8
  const int f0 = tid * 8;
  const int ar = tid >> 2;        // 0..127
  const int ac = (tid & 3) * 8;

  const int q = lane >> 4;        // quad -> k offset q*8, out-row base q*4
  const int r16 = lane & 15;

  floatx4 acc_g[4][2], acc_u[4][2];
#pragma unroll
  for (int i = 0; i < 4; i++)
#pragma unroll
    for (int j = 0; j < 2; j++) {
      acc_g[i][j] = (floatx4){0.f, 0.f, 0.f, 0.f};
      acc_u[i][j] = (floatx4){0.f, 0.f, 0.f, 0.f};
    }

  const unsigned short* ag = A + (size_t)(m0 + ar) * K + ac;
  const unsigned short* b1g = B1 + (size_t)(n0 + ar) * K + ac;
  const unsigned short* b3g = B3 + (size_t)(n0 + ar) * K + ac;

  for (int k0 = 0; k0 < K; k0 += 32) {
    load16_to_lds(ag + k0, &As[f0]);
    load16_to_lds(b1g + k0, &B1s[f0]);
    load16_to_lds(b3g + k0, &B3s[f0]);
    __syncthreads();

    short8 a[4], b1[2], b3[2];
#pragma unroll
    for (int t = 0; t < 4; t++)
      a[t] = *(const short8*)&As[(wm * 64 + t * 16 + r16) * 32 + q * 8];
#pragma unroll
    for (int j = 0; j < 2; j++) {
      b1[j] = *(const short8*)&B1s[(wn * 32 + j * 16 + r16) * 32 + q * 8];
      b3[j] = *(const short8*)&B3s[(wn * 32 + j * 16 + r16) * 32 + q * 8];
    }
#pragma unroll
    for (int i = 0; i < 4; i++)
#pragma unroll
      for (int j = 0; j < 2; j++) {
        acc_g[i][j] =
            __builtin_amdgcn_mfma_f32_16x16x32_bf16(a[i], b1[j], acc_g[i][j], 0, 0, 0);
        acc_u[i][j] =
            __builtin_amdgcn_mfma_f32_16x16x32_bf16(a[i], b3[j], acc_u[i][j], 0, 0, 0);
      }
    __syncthreads();
  }

  // epilogue: D col = lane&15, row = quad*4 + reg (m89/m91-verified);
  // fused = silu(g) * u computed on fp32 accumulators, written once as bf16.
#pragma unroll
  for (int i = 0; i < 4; i++) {
    int row0 = m0 + wm * 64 + i * 16 + q * 4;
#pragma unroll
    for (int j = 0; j < 2; j++) {
      int col = n0 + wn * 32 + j * 16 + r16;
#pragma unroll
      for (int rr = 0; rr < 4; rr++) {
        float gv = acc_g[i][j][rr];
        float uv = acc_u[i][j][rr];
        float sv = gv / (1.f + __expf(-gv)) * uv;
        C[(size_t)(row0 + rr) * N + col] = f2bf(sv);
      }
    }
  }
}

// ---------- GEMM: C[M,N] = A[M,K] * B[N,K]^T, bf16 in, fp32 out ----------
// Round-1 structure (m97-style), plain 2D grid (no swizzle — R2 showed the
// XCD strip swizzle cut HBM fetch but *raised* time; not HBM-bound).
__global__ __launch_bounds__(256) void gemm_nt_f32(
    const unsigned short* __restrict__ A,  // [M,K] bf16
    const unsigned short* __restrict__ B,  // [N,K] bf16
    float* __restrict__ C,                 // [M,N] fp32
    int M, int N, int K) {
  __shared__ unsigned short As[128 * 32];
  __shared__ unsigned short Bs[128 * 32];

  const int tid = threadIdx.x;
  const int lane = tid & 63;
  const int wave = tid >> 6;
  const int wm = wave >> 1, wn = wave & 1;
  const int m0 = blockIdx.y * 128, n0 = blockIdx.x * 128;

  const int f0 = tid * 8;
  const int ar = f0 >> 5;
  const int ac = f0 & 31;

  const int q = lane >> 4;
  const int r16 = lane & 15;

  floatx4 acc[4][4];
#pragma unroll
  for (int i = 0; i < 4; i++)
#pragma unroll
    for (int j = 0; j < 4; j++) acc[i][j] = (floatx4){0.f, 0.f, 0.f, 0.f};

  const unsigned short* Abase = A + (size_t)m0 * K;
  const unsigned short* Bbase = B + (size_t)n0 * K;

  for (int k0 = 0; k0 < K; k0 += 32) {
    load16_to_lds(Abase + (size_t)ar * K + k0 + ac, &As[f0]);
    load16_to_lds(Abase + (size_t)(64 + ar) * K + k0 + ac, &As[2048 + f0]);
    load16_to_lds(Bbase + (size_t)ar * K + k0 + ac, &Bs[f0]);
    load16_to_lds(Bbase + (size_t)(64 + ar) * K + k0 + ac, &Bs[2048 + f0]);
    __syncthreads();

    short8 a[4], b[4];
#pragma unroll
    for (int t = 0; t < 4; t++) {
      a[t] = *(const short8*)&As[(wm * 64 + t * 16 + r16) * 32 + q * 8];
      b[t] = *(const short8*)&Bs[(wn * 64 + t * 16 + r16) * 32 + q * 8];
    }
#pragma unroll
    for (int i = 0; i < 4; i++)
#pragma unroll
      for (int j = 0; j < 4; j++)
        acc[i][j] =
            __builtin_amdgcn_mfma_f32_16x16x32_bf16(a[i], b[j], acc[i][j], 0, 0, 0);
    __syncthreads();
  }

#pragma unroll
  for (int i = 0; i < 4; i++) {
    int row0 = m0 + wm * 64 + i * 16 + q * 4;
#pragma unroll
    for (int j = 0; j < 4; j++) {
      int col = n0 + wn * 64 + j * 16 + r16;
#pragma unroll
      for (int rr = 0; rr < 4; rr++)
        C[(size_t)(row0 + rr) * N + col] = acc[i][j][rr];
    }
  }
}

// ---------- launch ----------
extern "C" void kernel_launch(void* const* d_in, const int* in_sizes, int n_in,
                              void* d_out, int out_size, void* d_ws, size_t ws_size,
                              hipStream_t stream) {
  const float* x = (const float*)d_in[0];
  const float* w1q = (const float*)d_in[1];
  const float* w1s = (const float*)d_in[2];
  const float* w3q = (const float*)d_in[3];
  const float* w3s = (const float*)d_in[4];
  const float* w2q = (const float*)d_in[5];
  const float* w2s = (const float*)d_in[6];

  const int T = 4096, H = 2048, F = 7168;

  char* ws = (char*)d_ws;
  unsigned short* xb  = (unsigned short*)ws;  ws += (size_t)T * H * 2;   // 16.8 MB
  unsigned short* w1b = (unsigned short*)ws;  ws += (size_t)F * H * 2;   // 29.4 MB
  unsigned short* w3b = (unsigned short*)ws;  ws += (size_t)F * H * 2;   // 29.4 MB
  unsigned short* g   = (unsigned short*)ws;  ws += (size_t)T * F * 2;   // 58.7 MB
  unsigned short* w2b = w1b;  // reused after merged kernel consumes w1b
  // total ~134 MB of d_ws

  long xn4 = (long)T * H / 4;
  long wn4 = (long)F * H / 4;

  f32_to_bf16_kernel<<<(xn4 + 255) / 256, 256, 0, stream>>>(x, xb, xn4);
  dequant_kernel<<<(wn4 + 255) / 256, 256, 0, stream>>>(w1q, w1s, w1b, H, H / 128, wn4);
  dequant_kernel<<<(wn4 + 255) / 256, 256, 0, stream>>>(w3q, w3s, w3b, H, H / 128, wn4);

  // g = silu(x @ w1^T) * (x @ w3^T)  — single fused pass
  dual_gemm_silu<<<dim3(F / 128, T / 128), 512, 0, stream>>>(xb, w1b, w3b, g, T, F, H);

  // out = g @ w2^T  (fp32 out)
  dequant_kernel<<<(wn4 + 255) / 256, 256, 0, stream>>>(w2q, w2s, w2b, F, F / 128, wn4);
  gemm_nt_f32<<<dim3(H / 128, T / 128), 256, 0, stream>>>(g, w2b, (float*)d_out, T, H, F);
}